// Round 4
// baseline (950.590 us; speedup 1.0000x reference)
//
#include <hip/hip_runtime.h>
#include <hip/hip_bf16.h>

#define NB 8
#define CC 128
#define HH 112
#define WW 112
#define HWS (HH*WW)            // 12544
#define PLANE (CC*HWS)         // 1605632
#define TOT (NB*PLANE)         // 12845056

typedef __attribute__((ext_vector_type(8))) short short8v;
typedef __attribute__((ext_vector_type(4))) float float4v;

__device__ __forceinline__ float bflo(unsigned u){ return __uint_as_float(u<<16); }
__device__ __forceinline__ float bfhi(unsigned u){ return __uint_as_float(u & 0xffff0000u); }
__device__ __forceinline__ float ldv(const float* p, size_t i){ return p[i]; }
__device__ __forceinline__ float ldv(const ushort* p, size_t i){ return __uint_as_float(((unsigned)p[i])<<16); }
__device__ __forceinline__ void ld16(const ushort* p, float* v){
    uint4 u0 = *((const uint4*)p); uint4 u1 = *((const uint4*)(p+8));
    v[0]=bflo(u0.x); v[1]=bfhi(u0.x); v[2]=bflo(u0.y); v[3]=bfhi(u0.y);
    v[4]=bflo(u0.z); v[5]=bfhi(u0.z); v[6]=bflo(u0.w); v[7]=bfhi(u0.w);
    v[8]=bflo(u1.x); v[9]=bfhi(u1.x); v[10]=bflo(u1.y); v[11]=bfhi(u1.y);
    v[12]=bflo(u1.z); v[13]=bfhi(u1.z); v[14]=bflo(u1.w); v[15]=bfhi(u1.w);
}
__device__ __forceinline__ void ld16(const float* p, float* v){
    #pragma unroll
    for (int j=0;j<16;j++) v[j]=p[j];
}
__device__ __forceinline__ ushort f2bf(float f){
    unsigned u = __float_as_uint(f);
    return (ushort)((u + 0x7fffu + ((u>>16)&1u)) >> 16);
}
__device__ __forceinline__ void stv(float* o, size_t i, float v){ o[i]=v; }
__device__ __forceinline__ void stv(ushort* o, size_t i, float v){ o[i]=f2bf(v); }

// ---------------- K0: dtype probe. flag=1 -> inputs are fp32 ----------------
__global__ __launch_bounds__(256) void detect_k(const ushort* __restrict__ x, int* __restrict__ flag){
    __shared__ int cnt;
    if (threadIdx.x==0) cnt = 0;
    __syncthreads();
    int bad = 0;
    for (int i = threadIdx.x; i < 2048; i += 256){
        float v = ldv(x, i);
        if (!(v > -1e4f && v < 1e4f)) bad++;
    }
    atomicAdd(&cnt, bad);
    __syncthreads();
    if (threadIdx.x==0) *flag = (cnt > 64) ? 1 : 0;
}

// ---------------- KW1: Wpk[o][kappa=k*128+i] = bf16(w3[o,i,0,k]) ----------------
template<typename ET>
__device__ __forceinline__ void wpack_body(const ET* __restrict__ w3, ushort* __restrict__ Wpk){
    int idx = blockIdx.x*256 + threadIdx.x;
    if (idx < CC*384){
        int o = idx/384, kap = idx - o*384;
        int k = kap>>7, i = kap&127;
        Wpk[idx] = f2bf(ldv(w3, (o*128+i)*3 + k));
    }
}
__global__ __launch_bounds__(256) void wpack_k(const void* w3, ushort* Wpk, const int* fl){
    if (*fl) wpack_body((const float*)w3, Wpk); else wpack_body((const ushort*)w3, Wpk);
}

// ---------------- KB: Bbig[s][kappa] = bf16(silu(x)[i, y, x+2k-2]), fragment-ordered im2col ----------------
template<typename ET>
__device__ __forceinline__ void bbig_body(const ET* __restrict__ x, ushort* __restrict__ Bbig){
    int y = blockIdx.x, n = blockIdx.y;
    __shared__ ushort row[CC*120];
    const ET* xb = x + (size_t)n*PLANE + y*WW;
    for (int idx=threadIdx.x; idx<CC*WW; idx+=256){
        int i = idx/WW, xx = idx - i*WW;
        float v = ldv(xb, (size_t)i*HWS + xx);
        float sv = v * (1.f/(1.f+expf(-v)));
        row[i*120 + xx + 2] = f2bf(sv);
    }
    for (int idx=threadIdx.x; idx<CC*4; idx+=256){
        int i = idx>>2, j = idx&3;
        row[i*120 + (j<2 ? j : j+112)] = 0;
    }
    __syncthreads();
    ushort* ob = Bbig + ((size_t)(n*HWS + y*WW))*384;
    for (int idx=threadIdx.x; idx<WW*48; idx+=256){
        int xx = idx/48, c8 = idx - xx*48;
        int k = c8>>4, i0 = (c8&15)<<3, xp = xx + 2*k;
        ushort tmp[8];
        #pragma unroll
        for (int j=0;j<8;j++) tmp[j] = row[(i0+j)*120 + xp];
        *((short8v*)(ob + (size_t)xx*384 + c8*8)) = *((const short8v*)tmp);
    }
}
__global__ __launch_bounds__(256) void bbig_k(const void* x, ushort* Bbig, const int* fl){
    if (*fl) bbig_body((const float*)x, Bbig); else bbig_body((const ushort*)x, Bbig);
}

// ---------------- K2: t3 = A(128x384) * Bbig(384 x s) per n, LDS-free MFMA GEMM -> bf16 ----------------
__global__ __launch_bounds__(256) void conv3mm_k(const ushort* __restrict__ Bbig, const ushort* __restrict__ Wpk,
                                                 ushort* __restrict__ t3){
    int sb = blockIdx.x;        // 0..97
    int n  = blockIdx.y;
    int wid = threadIdx.x >> 6, lane = threadIdx.x & 63;
    int l15 = lane & 15, quad = lane >> 4;
    int s0 = sb*128 + wid*32;
    const ushort* bbase = Bbig + ((size_t)(n*HWS) + s0 + l15)*384 + quad*8;
    const ushort* abase = Wpk + (size_t)l15*384 + quad*8;
    float4v acc[8][2] = {};
    #pragma unroll
    for (int kc=0; kc<12; kc++){
        short8v b0 = *((const short8v*)(bbase + kc*32));
        short8v b1 = *((const short8v*)(bbase + 16*384 + kc*32));
        #pragma unroll
        for (int mt=0; mt<8; mt++){
            short8v a = *((const short8v*)(abase + (size_t)mt*16*384 + kc*32));
            acc[mt][0] = __builtin_amdgcn_mfma_f32_16x16x32_bf16(a, b0, acc[mt][0], 0,0,0);
            acc[mt][1] = __builtin_amdgcn_mfma_f32_16x16x32_bf16(a, b1, acc[mt][1], 0,0,0);
        }
    }
    ushort* tb = t3 + (size_t)n*PLANE;
    #pragma unroll
    for (int mt=0; mt<8; mt++){
        #pragma unroll
        for (int nt=0; nt<2; nt++){
            #pragma unroll
            for (int r=0; r<4; r++){
                int o = mt*16 + quad*4 + r;
                int s = s0 + nt*16 + l15;
                tb[(size_t)o*HWS + s] = f2bf(acc[mt][nt][r]);
            }
        }
    }
}

// ---------------- K3: depthwise conv(7,1) dil=(3,1) pad=(9,0), bf16 in/out, in-place safe ----------------
template<typename ET>
__device__ __forceinline__ void dwconv_body(const ushort* __restrict__ t3, const ET* __restrict__ w4,
                                            ushort* __restrict__ t4){
    int c = blockIdx.x & 127, n = blockIdx.x >> 7;
    __shared__ ushort pl[HWS];
    const ushort* src = t3 + (size_t)n*PLANE + c*HWS;
    for (int i=threadIdx.x; i<HWS/8; i+=256)
        ((short8v*)pl)[i] = ((const short8v*)src)[i];
    float wk[7];
    #pragma unroll
    for (int k=0;k<7;k++) wk[k]=ldv(w4, c*7+k);
    __syncthreads();
    ushort* dst = t4 + (size_t)n*PLANE + c*HWS;
    for (int i=threadIdx.x;i<HWS;i+=256){
        int y = i/WW, x = i - y*WW;
        float acc=0.f;
        #pragma unroll
        for (int k=0;k<7;k++){
            int yy = y-9+3*k;
            if (yy>=0 && yy<HH) acc = fmaf(wk[k], ldv(pl, yy*WW+x), acc);
        }
        dst[i]=f2bf(acc);
    }
}
__global__ __launch_bounds__(256) void dwconv_k(const ushort* t3, const void* w4, ushort* t4, const int* fl){
    if (*fl) dwconv_body(t3, (const float*)w4, t4); else dwconv_body(t3, (const ushort*)w4, t4);
}

// ---------------- KW2: Wfb[o][cl*7+k] = bf16(w15[o, cl*7+k] * w10[32g+cl, k]) ----------------
template<typename ET>
__device__ __forceinline__ void fusew_body(const ET* __restrict__ w10, const ET* __restrict__ w15,
                                           ushort* __restrict__ Wfb){
    int idx = blockIdx.x*256+threadIdx.x;
    if (idx < CC*224){
        int o = idx / 224, r = idx - o*224;
        int g = o >> 5;
        int cl = r/7, k = r - cl*7;
        int c = g*32 + cl;
        Wfb[idx] = f2bf(ldv(w15, o*224 + r) * ldv(w10, c*7+k));
    }
}
__global__ __launch_bounds__(256) void fusew_k(const void* w10, const void* w15, ushort* Wfb, const int* fl){
    if (*fl) fusew_body((const float*)w10, (const float*)w15, Wfb);
    else     fusew_body((const ushort*)w10, (const ushort*)w15, Wfb);
}

// ---------------- KI: B[(nn,g)][s=(y,x)][kappa=cl*7+k] = bf16(t4[(32g+cl-2)&127, y+2k-6, x]) ----------------
__global__ __launch_bounds__(256) void imcol_k(const ushort* __restrict__ t4, ushort* __restrict__ B, int n0){
    int y = blockIdx.x, g = blockIdx.y, nn = blockIdx.z;   // nn 0..3
    int n = n0 + nn;
    __shared__ ushort sm[224*WW];   // [kappa][x], 49KB
    const ushort* tb = t4 + (size_t)n*PLANE;
    for (int idx=threadIdx.x; idx<224*WW; idx+=256){
        int kap = idx/WW, x = idx - kap*WW;
        int cl = kap/7, k = kap - cl*7;
        int row = y + 2*k - 6;
        int ch = (g*32 + cl - 2) & 127;
        sm[idx] = (row>=0 && row<HH) ? tb[(size_t)ch*HWS + row*WW + x] : (ushort)0;
    }
    __syncthreads();
    ushort* ob = B + ((size_t)(nn*4+g)*HWS + y*WW)*224;
    for (int idx=threadIdx.x; idx<WW*28; idx+=256){
        int x = idx/28, c8 = idx - x*28;
        ushort tmp[8];
        #pragma unroll
        for (int j=0;j<8;j++) tmp[j] = sm[(c8*8+j)*WW + x];
        *((short8v*)(ob + (size_t)x*224 + c8*8)) = *((const short8v*)tmp);
    }
}

// ---------------- K6: u = Wfb(32x224 per g) * B(224 x s), grouped MFMA GEMM -> bf16 ----------------
__global__ __launch_bounds__(256) void t15mm_k(const ushort* __restrict__ B, const ushort* __restrict__ Wfb,
                                               ushort* __restrict__ u, int n0){
    int sb = blockIdx.x, g = blockIdx.y, nn = blockIdx.z;
    int wid = threadIdx.x>>6, lane = threadIdx.x&63;
    int l15 = lane&15, quad = lane>>4;
    int s0 = sb*128 + wid*32;
    const ushort* bbase = B + ((size_t)(nn*4+g)*HWS + s0 + l15)*224 + quad*8;
    const ushort* abase = Wfb + (size_t)(g*32 + l15)*224 + quad*8;
    float4v acc[2][2] = {};
    #pragma unroll
    for (int kc=0;kc<7;kc++){
        short8v b0 = *((const short8v*)(bbase + kc*32));
        short8v b1 = *((const short8v*)(bbase + 16*224 + kc*32));
        short8v a0 = *((const short8v*)(abase + kc*32));
        short8v a1 = *((const short8v*)(abase + 16*224 + kc*32));
        acc[0][0] = __builtin_amdgcn_mfma_f32_16x16x32_bf16(a0, b0, acc[0][0], 0,0,0);
        acc[0][1] = __builtin_amdgcn_mfma_f32_16x16x32_bf16(a0, b1, acc[0][1], 0,0,0);
        acc[1][0] = __builtin_amdgcn_mfma_f32_16x16x32_bf16(a1, b0, acc[1][0], 0,0,0);
        acc[1][1] = __builtin_amdgcn_mfma_f32_16x16x32_bf16(a1, b1, acc[1][1], 0,0,0);
    }
    int n = n0 + nn;
    #pragma unroll
    for (int mt=0;mt<2;mt++){
        #pragma unroll
        for (int nt=0;nt<2;nt++){
            #pragma unroll
            for (int r=0;r<4;r++){
                int o = g*32 + mt*16 + quad*4 + r;
                int s = s0 + nt*16 + l15;
                u[((size_t)n*CC + o)*HWS + s] = f2bf(acc[mt][nt][r]);
            }
        }
    }
}

// ---------------- K4: t5raw[n,ci,cj] = sum_s sigmoid(x[n,ci,s]) * x[n,cj,s]  (atomic K-split x64) ----------------
template<typename ET>
__device__ __forceinline__ void t5_body(const ET* __restrict__ x, float* __restrict__ t5){
    int kc = blockIdx.x, n = blockIdx.y;   // kc in 0..63
    __shared__ float sA[32][136];
    __shared__ float sB[32][136];
    float acc[8][8] = {};
    int tid = threadIdx.x, ty = tid>>4, tx = tid&15;
    int lch = tid>>1, lhalf = tid&1;
    const ET* xb = x + (size_t)n*PLANE;
    for (int s0 = kc*32; s0 < HWS; s0 += 64*32){
        const ET* p = xb + (size_t)lch*HWS + s0 + lhalf*16;
        float v[16]; ld16(p, v);
        #pragma unroll
        for (int j=0;j<16;j++){
            sB[lhalf*16+j][lch] = v[j];
            sA[lhalf*16+j][lch] = 1.f/(1.f+expf(-v[j]));
        }
        __syncthreads();
        #pragma unroll 4
        for (int kk=0;kk<32;kk++){
            float a[8], b[8];
            *(float4*)&a[0] = *((const float4*)&sA[kk][ty*8]);
            *(float4*)&a[4] = *((const float4*)&sA[kk][ty*8+4]);
            *(float4*)&b[0] = *((const float4*)&sB[kk][tx*8]);
            *(float4*)&b[4] = *((const float4*)&sB[kk][tx*8+4]);
            #pragma unroll
            for (int i=0;i<8;i++)
                #pragma unroll
                for (int j=0;j<8;j++)
                    acc[i][j] = fmaf(a[i], b[j], acc[i][j]);
        }
        __syncthreads();
    }
    float* t5n = t5 + n*16384;
    #pragma unroll
    for (int i=0;i<8;i++)
        #pragma unroll
        for (int j=0;j<8;j++)
            atomicAdd(&t5n[(ty*8+i)*128 + (tx*8+j)], acc[i][j]);
}
__global__ __launch_bounds__(256) void t5_k(const void* x, float* t5, const int* fl){
    if (*fl) t5_body((const float*)x, t5); else t5_body((const ushort*)x, t5);
}

// ---------------- K5: out = u[shifted] + sc * sum_c (w9[c,d]*t5[n,c,d]) * silu(x)[n,c,s] ----------------
template<typename ET, typename OT>
__device__ __forceinline__ void final_body(const ET* __restrict__ x, const float* __restrict__ t5,
                                           const ET* __restrict__ w9, const ushort* __restrict__ u,
                                           OT* __restrict__ out){
    int st = blockIdx.x, dt = blockIdx.y, n = blockIdx.z;
    int s0 = st*64, d0 = dt*64;
    __shared__ float sA[16][68];
    __shared__ float sB[16][68];
    float acc[4][4]={};
    int tid=threadIdx.x, ty=tid>>4, tx=tid&15;
    const float sc = 7.89181775e-4f;   // 1/(sqrt(12544)*sqrt(128))
    const float* t5n = t5 + n*16384;
    const ET* xn = x + (size_t)n*PLANE;
    for (int c0=0; c0<CC; c0+=16){
        for (int idx=tid; idx<1024; idx+=256){
            int cl = idx>>6, dl = idx&63;
            int c = c0+cl;
            sA[cl][dl] = ldv(w9, c*128 + d0+dl) * t5n[c*128 + d0+dl] * sc;
            float v = ldv(xn, (size_t)c*HWS + s0 + dl);
            sB[cl][dl] = v * (1.f/(1.f+expf(-v)));
        }
        __syncthreads();
        #pragma unroll 4
        for (int kk=0;kk<16;kk++){
            float4 a = *((const float4*)&sA[kk][ty*4]);
            float4 b = *((const float4*)&sB[kk][tx*4]);
            acc[0][0]=fmaf(a.x,b.x,acc[0][0]); acc[0][1]=fmaf(a.x,b.y,acc[0][1]);
            acc[0][2]=fmaf(a.x,b.z,acc[0][2]); acc[0][3]=fmaf(a.x,b.w,acc[0][3]);
            acc[1][0]=fmaf(a.y,b.x,acc[1][0]); acc[1][1]=fmaf(a.y,b.y,acc[1][1]);
            acc[1][2]=fmaf(a.y,b.z,acc[1][2]); acc[1][3]=fmaf(a.y,b.w,acc[1][3]);
            acc[2][0]=fmaf(a.z,b.x,acc[2][0]); acc[2][1]=fmaf(a.z,b.y,acc[2][1]);
            acc[2][2]=fmaf(a.z,b.z,acc[2][2]); acc[2][3]=fmaf(a.z,b.w,acc[2][3]);
            acc[3][0]=fmaf(a.w,b.x,acc[3][0]); acc[3][1]=fmaf(a.w,b.y,acc[3][1]);
            acc[3][2]=fmaf(a.w,b.z,acc[3][2]); acc[3][3]=fmaf(a.w,b.w,acc[3][3]);
        }
        __syncthreads();
    }
    #pragma unroll
    for (int i=0;i<4;i++){
        int d = d0 + ty*4 + i;
        const ushort* un = u + ((size_t)n*CC+d)*HWS;
        #pragma unroll
        for (int j=0;j<4;j++){
            int s = s0 + tx*4 + j;
            int y = s/WW, xx = s - y*WW;
            int ys = y+2; if (ys>=HH) ys-=HH;
            int xs = xx-2; if (xs<0) xs+=WW;
            float val = ldv(un, ys*WW + xs) + acc[i][j];
            stv(out, ((size_t)n*CC+d)*HWS + s, val);
        }
    }
}
__global__ __launch_bounds__(256) void final_k(const void* x, const float* t5, const void* w9,
                                               const ushort* u, void* out, const int* fl){
    if (*fl) final_body((const float*)x, t5, (const float*)w9, u, (float*)out);
    else     final_body((const ushort*)x, t5, (const ushort*)w9, u, (ushort*)out);
}

extern "C" void kernel_launch(void* const* d_in, const int* in_sizes, int n_in,
                              void* d_out, int out_size, void* d_ws, size_t ws_size,
                              hipStream_t stream) {
    const void* x   = d_in[0];
    const void* w3  = d_in[1];
    const void* w4  = d_in[2];
    const void* w9  = d_in[3];
    const void* w10 = d_in[4];
    const void* w15 = d_in[5];

    float* ws = (float*)d_ws;
    // t3/t4/u region: TOT ushorts (bf16), 25.7MB. u aliases consumed t4 slices (see chunk ordering).
    ushort* t3 = (ushort*)ws;
    ushort* u  = t3;
    // buf region: 90MB. Hosts Bbig (77MB) then per-chunk Bt15 (4n*4g*HWS*224 ushorts = 90MB).
    ushort* buf = t3 + TOT;
    float* t5   = (float*)(buf + (size_t)16*HWS*224);   // after buf
    ushort* Wfb = (ushort*)(t5 + NB*CC*CC);             // 28672
    ushort* Wpk = Wfb + CC*224;                          // 49152
    int* flag   = (int*)(Wpk + CC*384);

    detect_k<<<1, 256, 0, stream>>>((const ushort*)x, flag);
    hipMemsetAsync(t5, 0, NB*CC*CC*sizeof(float), stream);

    wpack_k <<<192, 256, 0, stream>>>(w3, Wpk, flag);
    fusew_k <<<112, 256, 0, stream>>>(w10, w15, Wfb, flag);
    bbig_k  <<<dim3(HH,NB), 256, 0, stream>>>(x, buf, flag);
    conv3mm_k<<<dim3(98,NB), 256, 0, stream>>>(buf, Wpk, t3);
    dwconv_k<<<NB*CC, 256, 0, stream>>>(t3, w4, t3, flag);   // in-place, t3 now holds t4
    t5_k    <<<dim3(64,NB), 256, 0, stream>>>(x, t5, flag);
    // chunk 0: n=0..3.  imcol reads t4[n0..3]; t15mm writes u[n0..3] over consumed t4[n0..1]
    imcol_k <<<dim3(HH,4,4), 256, 0, stream>>>(t3, buf, 0);
    t15mm_k <<<dim3(98,4,4), 256, 0, stream>>>(buf, Wfb, u, 0);
    // chunk 1: n=4..7. imcol reads t4[n4..7] (untouched); t15mm writes u[n4..7] over consumed t4[n2..3]
    imcol_k <<<dim3(HH,4,4), 256, 0, stream>>>(t3, buf, 4);
    t15mm_k <<<dim3(98,4,4), 256, 0, stream>>>(buf, Wfb, u, 4);
    final_k <<<dim3(HWS/64, CC/64, NB), 256, 0, stream>>>(x, t5, w9, u, d_out, flag);
}

// Round 5
// 647.985 us; speedup vs baseline: 1.4670x; 1.4670x over previous
//
#include <hip/hip_runtime.h>
#include <hip/hip_bf16.h>

#define NB 8
#define CC 128
#define HH 112
#define WW 112
#define HWS (HH*WW)            // 12544
#define PLANE (CC*HWS)         // 1605632
#define TOT (NB*PLANE)         // 12845056

typedef __attribute__((ext_vector_type(8))) short short8v;
typedef __attribute__((ext_vector_type(4))) float float4v;

__device__ __forceinline__ float bflo(unsigned u){ return __uint_as_float(u<<16); }
__device__ __forceinline__ float bfhi(unsigned u){ return __uint_as_float(u & 0xffff0000u); }
__device__ __forceinline__ float ldv(const float* p, size_t i){ return p[i]; }
__device__ __forceinline__ float ldv(const ushort* p, size_t i){ return __uint_as_float(((unsigned)p[i])<<16); }
__device__ __forceinline__ void ld8(const ushort* p, float* v){
    uint4 u0 = *((const uint4*)p);
    v[0]=bflo(u0.x); v[1]=bfhi(u0.x); v[2]=bflo(u0.y); v[3]=bfhi(u0.y);
    v[4]=bflo(u0.z); v[5]=bfhi(u0.z); v[6]=bflo(u0.w); v[7]=bfhi(u0.w);
}
__device__ __forceinline__ void ld8(const float* p, float* v){
    float4 a = *((const float4*)p); float4 b = *((const float4*)(p+4));
    v[0]=a.x; v[1]=a.y; v[2]=a.z; v[3]=a.w; v[4]=b.x; v[5]=b.y; v[6]=b.z; v[7]=b.w;
}
__device__ __forceinline__ ushort f2bf(float f){
    unsigned u = __float_as_uint(f);
    return (ushort)((u + 0x7fffu + ((u>>16)&1u)) >> 16);
}
__device__ __forceinline__ void stv(float* o, size_t i, float v){ o[i]=v; }
__device__ __forceinline__ void stv(ushort* o, size_t i, float v){ o[i]=f2bf(v); }

// ---------------- K0: dtype probe. flag=1 -> inputs are fp32 ----------------
__global__ __launch_bounds__(256) void detect_k(const ushort* __restrict__ x, int* __restrict__ flag){
    __shared__ int cnt;
    if (threadIdx.x==0) cnt = 0;
    __syncthreads();
    int bad = 0;
    for (int i = threadIdx.x; i < 2048; i += 256){
        float v = ldv(x, i);
        if (!(v > -1e4f && v < 1e4f)) bad++;
    }
    atomicAdd(&cnt, bad);
    __syncthreads();
    if (threadIdx.x==0) *flag = (cnt > 64) ? 1 : 0;
}

// ---------------- KW1: Wpk[o][kappa=k*128+i] = bf16(w3[o,i,0,k]) ----------------
template<typename ET>
__device__ __forceinline__ void wpack_body(const ET* __restrict__ w3, ushort* __restrict__ Wpk){
    int idx = blockIdx.x*256 + threadIdx.x;
    if (idx < CC*384){
        int o = idx/384, kap = idx - o*384;
        int k = kap>>7, i = kap&127;
        Wpk[idx] = f2bf(ldv(w3, (o*128+i)*3 + k));
    }
}
__global__ __launch_bounds__(256) void wpack_k(const void* w3, ushort* Wpk, const int* fl){
    if (*fl) wpack_body((const float*)w3, Wpk); else wpack_body((const ushort*)w3, Wpk);
}

// ---------------- KB: Bbig[s][kappa] = bf16(silu(x)[i, y, x+2k-2]), fragment-ordered im2col ----------------
template<typename ET>
__device__ __forceinline__ void bbig_body(const ET* __restrict__ x, ushort* __restrict__ Bbig){
    int y = blockIdx.x, n = blockIdx.y;
    __shared__ ushort row[CC*120];
    const ET* xb = x + (size_t)n*PLANE + y*WW;
    for (int idx=threadIdx.x; idx<CC*WW; idx+=256){
        int i = idx/WW, xx = idx - i*WW;
        float v = ldv(xb, (size_t)i*HWS + xx);
        float sv = v * (1.f/(1.f+expf(-v)));
        row[i*120 + xx + 2] = f2bf(sv);
    }
    for (int idx=threadIdx.x; idx<CC*4; idx+=256){
        int i = idx>>2, j = idx&3;
        row[i*120 + (j<2 ? j : j+112)] = 0;
    }
    __syncthreads();
    ushort* ob = Bbig + ((size_t)(n*HWS + y*WW))*384;
    for (int idx=threadIdx.x; idx<WW*48; idx+=256){
        int xx = idx/48, c8 = idx - xx*48;
        int k = c8>>4, i0 = (c8&15)<<3, xp = xx + 2*k;
        ushort tmp[8];
        #pragma unroll
        for (int j=0;j<8;j++) tmp[j] = row[(i0+j)*120 + xp];
        *((short8v*)(ob + (size_t)xx*384 + c8*8)) = *((const short8v*)tmp);
    }
}
__global__ __launch_bounds__(256) void bbig_k(const void* x, ushort* Bbig, const int* fl){
    if (*fl) bbig_body((const float*)x, Bbig); else bbig_body((const ushort*)x, Bbig);
}

// ---------------- K2: t3 = A(128x384) * Bbig(384 x s) per n, LDS-free MFMA GEMM -> bf16 ----------------
__global__ __launch_bounds__(256) void conv3mm_k(const ushort* __restrict__ Bbig, const ushort* __restrict__ Wpk,
                                                 ushort* __restrict__ t3){
    int sb = blockIdx.x;        // 0..97
    int n  = blockIdx.y;
    int wid = threadIdx.x >> 6, lane = threadIdx.x & 63;
    int l15 = lane & 15, quad = lane >> 4;
    int s0 = sb*128 + wid*32;
    const ushort* bbase = Bbig + ((size_t)(n*HWS) + s0 + l15)*384 + quad*8;
    const ushort* abase = Wpk + (size_t)l15*384 + quad*8;
    float4v acc[8][2] = {};
    #pragma unroll
    for (int kc=0; kc<12; kc++){
        short8v b0 = *((const short8v*)(bbase + kc*32));
        short8v b1 = *((const short8v*)(bbase + 16*384 + kc*32));
        #pragma unroll
        for (int mt=0; mt<8; mt++){
            short8v a = *((const short8v*)(abase + (size_t)mt*16*384 + kc*32));
            acc[mt][0] = __builtin_amdgcn_mfma_f32_16x16x32_bf16(a, b0, acc[mt][0], 0,0,0);
            acc[mt][1] = __builtin_amdgcn_mfma_f32_16x16x32_bf16(a, b1, acc[mt][1], 0,0,0);
        }
    }
    ushort* tb = t3 + (size_t)n*PLANE;
    #pragma unroll
    for (int mt=0; mt<8; mt++){
        #pragma unroll
        for (int nt=0; nt<2; nt++){
            #pragma unroll
            for (int r=0; r<4; r++){
                int o = mt*16 + quad*4 + r;
                int s = s0 + nt*16 + l15;
                tb[(size_t)o*HWS + s] = f2bf(acc[mt][nt][r]);
            }
        }
    }
}

// ---------------- K3: depthwise conv(7,1) dil=(3,1) pad=(9,0), bf16 in/out, in-place safe ----------------
template<typename ET>
__device__ __forceinline__ void dwconv_body(const ushort* __restrict__ t3, const ET* __restrict__ w4,
                                            ushort* __restrict__ t4){
    int c = blockIdx.x & 127, n = blockIdx.x >> 7;
    __shared__ ushort pl[HWS];
    const ushort* src = t3 + (size_t)n*PLANE + c*HWS;
    for (int i=threadIdx.x; i<HWS/8; i+=256)
        ((short8v*)pl)[i] = ((const short8v*)src)[i];
    float wk[7];
    #pragma unroll
    for (int k=0;k<7;k++) wk[k]=ldv(w4, c*7+k);
    __syncthreads();
    ushort* dst = t4 + (size_t)n*PLANE + c*HWS;
    for (int i=threadIdx.x;i<HWS;i+=256){
        int y = i/WW, x = i - y*WW;
        float acc=0.f;
        #pragma unroll
        for (int k=0;k<7;k++){
            int yy = y-9+3*k;
            if (yy>=0 && yy<HH) acc = fmaf(wk[k], ldv(pl, yy*WW+x), acc);
        }
        dst[i]=f2bf(acc);
    }
}
__global__ __launch_bounds__(256) void dwconv_k(const ushort* t3, const void* w4, ushort* t4, const int* fl){
    if (*fl) dwconv_body(t3, (const float*)w4, t4); else dwconv_body(t3, (const ushort*)w4, t4);
}

// ---------------- KW2: Wfb[o][cl*7+k] = bf16(w15[o, cl*7+k] * w10[32g+cl, k]) ----------------
template<typename ET>
__device__ __forceinline__ void fusew_body(const ET* __restrict__ w10, const ET* __restrict__ w15,
                                           ushort* __restrict__ Wfb){
    int idx = blockIdx.x*256+threadIdx.x;
    if (idx < CC*224){
        int o = idx / 224, r = idx - o*224;
        int g = o >> 5;
        int cl = r/7, k = r - cl*7;
        int c = g*32 + cl;
        Wfb[idx] = f2bf(ldv(w15, o*224 + r) * ldv(w10, c*7+k));
    }
}
__global__ __launch_bounds__(256) void fusew_k(const void* w10, const void* w15, ushort* Wfb, const int* fl){
    if (*fl) fusew_body((const float*)w10, (const float*)w15, Wfb);
    else     fusew_body((const ushort*)w10, (const ushort*)w15, Wfb);
}

// ---------------- KI: B[(nn,g)][s=(y,x)][kappa=cl*7+k] = bf16(t4[(32g+cl-2)&127, y+2k-6, x]) ----------------
// LDS row stride 113 (not 112): breaks the 28-way bank conflict on the transpose gather
__global__ __launch_bounds__(256) void imcol_k(const ushort* __restrict__ t4, ushort* __restrict__ B, int n0){
    int y = blockIdx.x, g = blockIdx.y, nn = blockIdx.z;   // nn 0..3
    int n = n0 + nn;
    __shared__ ushort sm[224*113];   // [kappa][x+pad]
    const ushort* tb = t4 + (size_t)n*PLANE;
    for (int idx=threadIdx.x; idx<224*WW; idx+=256){
        int kap = idx/WW, x = idx - kap*WW;
        int cl = kap/7, k = kap - cl*7;
        int row = y + 2*k - 6;
        int ch = (g*32 + cl - 2) & 127;
        sm[kap*113 + x] = (row>=0 && row<HH) ? tb[(size_t)ch*HWS + row*WW + x] : (ushort)0;
    }
    __syncthreads();
    ushort* ob = B + ((size_t)(nn*4+g)*HWS + y*WW)*224;
    for (int idx=threadIdx.x; idx<WW*28; idx+=256){
        int x = idx/28, c8 = idx - x*28;
        ushort tmp[8];
        #pragma unroll
        for (int j=0;j<8;j++) tmp[j] = sm[(c8*8+j)*113 + x];
        *((short8v*)(ob + (size_t)x*224 + c8*8)) = *((const short8v*)tmp);
    }
}

// ---------------- K6: u = Wfb(32x224 per g) * B(224 x s), grouped MFMA GEMM -> bf16 ----------------
__global__ __launch_bounds__(256) void t15mm_k(const ushort* __restrict__ B, const ushort* __restrict__ Wfb,
                                               ushort* __restrict__ u, int n0){
    int sb = blockIdx.x, g = blockIdx.y, nn = blockIdx.z;
    int wid = threadIdx.x>>6, lane = threadIdx.x&63;
    int l15 = lane&15, quad = lane>>4;
    int s0 = sb*128 + wid*32;
    const ushort* bbase = B + ((size_t)(nn*4+g)*HWS + s0 + l15)*224 + quad*8;
    const ushort* abase = Wfb + (size_t)(g*32 + l15)*224 + quad*8;
    float4v acc[2][2] = {};
    #pragma unroll
    for (int kc=0;kc<7;kc++){
        short8v b0 = *((const short8v*)(bbase + kc*32));
        short8v b1 = *((const short8v*)(bbase + 16*224 + kc*32));
        short8v a0 = *((const short8v*)(abase + kc*32));
        short8v a1 = *((const short8v*)(abase + 16*224 + kc*32));
        acc[0][0] = __builtin_amdgcn_mfma_f32_16x16x32_bf16(a0, b0, acc[0][0], 0,0,0);
        acc[0][1] = __builtin_amdgcn_mfma_f32_16x16x32_bf16(a0, b1, acc[0][1], 0,0,0);
        acc[1][0] = __builtin_amdgcn_mfma_f32_16x16x32_bf16(a1, b0, acc[1][0], 0,0,0);
        acc[1][1] = __builtin_amdgcn_mfma_f32_16x16x32_bf16(a1, b1, acc[1][1], 0,0,0);
    }
    int n = n0 + nn;
    #pragma unroll
    for (int mt=0;mt<2;mt++){
        #pragma unroll
        for (int nt=0;nt<2;nt++){
            #pragma unroll
            for (int r=0;r<4;r++){
                int o = g*32 + mt*16 + quad*4 + r;
                int s = s0 + nt*16 + l15;
                u[((size_t)n*CC + o)*HWS + s] = f2bf(acc[mt][nt][r]);
            }
        }
    }
}

// ---------------- K4: t5[n,ci,cj] += sum_s sigmoid(x[ci,s]) * x[cj,s] — LDS-free MFMA, K-split x49 ----------------
template<typename ET>
__device__ __forceinline__ void t5mm_body(const ET* __restrict__ x, float* __restrict__ t5){
    int ks = blockIdx.x, n = blockIdx.y;    // ks 0..48, 12544 = 49*256
    int wid = threadIdx.x>>6, lane = threadIdx.x&63;
    int l15 = lane&15, quad = lane>>4;
    const ET* xn = x + (size_t)n*PLANE;
    float4v acc[2][8] = {};
    for (int t=0; t<8; t++){
        int sb = ks*256 + t*32 + quad*8;
        short8v afr[2];
        #pragma unroll
        for (int mt=0; mt<2; mt++){
            int row = wid*32 + mt*16 + l15;
            float v[8]; ld8(xn + (size_t)row*HWS + sb, v);
            ushort tmp[8];
            #pragma unroll
            for (int j=0;j<8;j++) tmp[j] = f2bf(1.f/(1.f+expf(-v[j])));
            afr[mt] = *((const short8v*)tmp);
        }
        #pragma unroll
        for (int nt=0; nt<8; nt++){
            int row = nt*16 + l15;
            float v[8]; ld8(xn + (size_t)row*HWS + sb, v);
            ushort tmp[8];
            #pragma unroll
            for (int j=0;j<8;j++) tmp[j] = f2bf(v[j]);
            short8v bfr = *((const short8v*)tmp);
            acc[0][nt] = __builtin_amdgcn_mfma_f32_16x16x32_bf16(afr[0], bfr, acc[0][nt], 0,0,0);
            acc[1][nt] = __builtin_amdgcn_mfma_f32_16x16x32_bf16(afr[1], bfr, acc[1][nt], 0,0,0);
        }
    }
    float* t5n = t5 + n*16384;
    #pragma unroll
    for (int mt=0; mt<2; mt++){
        #pragma unroll
        for (int nt=0; nt<8; nt++){
            #pragma unroll
            for (int r=0; r<4; r++){
                int ci = wid*32 + mt*16 + quad*4 + r;   // sigmoid side (row)
                int cj = nt*16 + l15;                   // raw side (col)
                atomicAdd(&t5n[ci*128 + cj], acc[mt][nt][r]);
            }
        }
    }
}
__global__ __launch_bounds__(256) void t5mm_k(const void* x, float* t5, const int* fl){
    if (*fl) t5mm_body((const float*)x, t5); else t5mm_body((const ushort*)x, t5);
}

// ---------------- K5: out = u[shifted] + sc * sum_c (w9[c,d]*t5[n,c,d]) * silu(x)[n,c,s] ----------------
template<typename ET, typename OT>
__device__ __forceinline__ void final_body(const ET* __restrict__ x, const float* __restrict__ t5,
                                           const ET* __restrict__ w9, const ushort* __restrict__ u,
                                           OT* __restrict__ out){
    int st = blockIdx.x, dt = blockIdx.y, n = blockIdx.z;
    int s0 = st*64, d0 = dt*64;
    __shared__ float sA[16][68];
    __shared__ float sB[16][68];
    float acc[4][4]={};
    int tid=threadIdx.x, ty=tid>>4, tx=tid&15;
    const float sc = 7.89181775e-4f;   // 1/(sqrt(12544)*sqrt(128))
    const float* t5n = t5 + n*16384;
    const ET* xn = x + (size_t)n*PLANE;
    for (int c0=0; c0<CC; c0+=16){
        for (int idx=tid; idx<1024; idx+=256){
            int cl = idx>>6, dl = idx&63;
            int c = c0+cl;
            sA[cl][dl] = ldv(w9, c*128 + d0+dl) * t5n[c*128 + d0+dl] * sc;
            float v = ldv(xn, (size_t)c*HWS + s0 + dl);
            sB[cl][dl] = v * (1.f/(1.f+expf(-v)));
        }
        __syncthreads();
        #pragma unroll 4
        for (int kk=0;kk<16;kk++){
            float4 a = *((const float4*)&sA[kk][ty*4]);
            float4 b = *((const float4*)&sB[kk][tx*4]);
            acc[0][0]=fmaf(a.x,b.x,acc[0][0]); acc[0][1]=fmaf(a.x,b.y,acc[0][1]);
            acc[0][2]=fmaf(a.x,b.z,acc[0][2]); acc[0][3]=fmaf(a.x,b.w,acc[0][3]);
            acc[1][0]=fmaf(a.y,b.x,acc[1][0]); acc[1][1]=fmaf(a.y,b.y,acc[1][1]);
            acc[1][2]=fmaf(a.y,b.z,acc[1][2]); acc[1][3]=fmaf(a.y,b.w,acc[1][3]);
            acc[2][0]=fmaf(a.z,b.x,acc[2][0]); acc[2][1]=fmaf(a.z,b.y,acc[2][1]);
            acc[2][2]=fmaf(a.z,b.z,acc[2][2]); acc[2][3]=fmaf(a.z,b.w,acc[2][3]);
            acc[3][0]=fmaf(a.w,b.x,acc[3][0]); acc[3][1]=fmaf(a.w,b.y,acc[3][1]);
            acc[3][2]=fmaf(a.w,b.z,acc[3][2]); acc[3][3]=fmaf(a.w,b.w,acc[3][3]);
        }
        __syncthreads();
    }
    #pragma unroll
    for (int i=0;i<4;i++){
        int d = d0 + ty*4 + i;
        const ushort* un = u + ((size_t)n*CC+d)*HWS;
        #pragma unroll
        for (int j=0;j<4;j++){
            int s = s0 + tx*4 + j;
            int y = s/WW, xx = s - y*WW;
            int ys = y+2; if (ys>=HH) ys-=HH;
            int xs = xx-2; if (xs<0) xs+=WW;
            float val = ldv(un, ys*WW + xs) + acc[i][j];
            stv(out, ((size_t)n*CC+d)*HWS + s, val);
        }
    }
}
__global__ __launch_bounds__(256) void final_k(const void* x, const float* t5, const void* w9,
                                               const ushort* u, void* out, const int* fl){
    if (*fl) final_body((const float*)x, t5, (const float*)w9, u, (float*)out);
    else     final_body((const ushort*)x, t5, (const ushort*)w9, u, (ushort*)out);
}

extern "C" void kernel_launch(void* const* d_in, const int* in_sizes, int n_in,
                              void* d_out, int out_size, void* d_ws, size_t ws_size,
                              hipStream_t stream) {
    const void* x   = d_in[0];
    const void* w3  = d_in[1];
    const void* w4  = d_in[2];
    const void* w9  = d_in[3];
    const void* w10 = d_in[4];
    const void* w15 = d_in[5];

    float* ws = (float*)d_ws;
    // t3/t4/u region: TOT ushorts (bf16). u aliases consumed t4 slices (see chunk ordering).
    ushort* t3 = (ushort*)ws;
    ushort* u  = t3;
    // buf region: hosts Bbig (77MB) then per-chunk Bt15 (16*HWS*224 ushorts = 90MB).
    ushort* buf = t3 + TOT;
    float* t5   = (float*)(buf + (size_t)16*HWS*224);
    ushort* Wfb = (ushort*)(t5 + NB*CC*CC);
    ushort* Wpk = Wfb + CC*224;
    int* flag   = (int*)(Wpk + CC*384);

    detect_k<<<1, 256, 0, stream>>>((const ushort*)x, flag);
    hipMemsetAsync(t5, 0, NB*CC*CC*sizeof(float), stream);

    wpack_k <<<192, 256, 0, stream>>>(w3, Wpk, flag);
    fusew_k <<<112, 256, 0, stream>>>(w10, w15, Wfb, flag);
    bbig_k  <<<dim3(HH,NB), 256, 0, stream>>>(x, buf, flag);
    conv3mm_k<<<dim3(98,NB), 256, 0, stream>>>(buf, Wpk, t3);
    dwconv_k<<<NB*CC, 256, 0, stream>>>(t3, w4, t3, flag);   // in-place, t3 now holds t4
    t5mm_k  <<<dim3(49,NB), 256, 0, stream>>>(x, t5, flag);
    // chunk 0: n=0..3.  imcol reads t4[n0..3]; t15mm writes u[n0..3] over consumed t4[n0..1]
    imcol_k <<<dim3(HH,4,4), 256, 0, stream>>>(t3, buf, 0);
    t15mm_k <<<dim3(98,4,4), 256, 0, stream>>>(buf, Wfb, u, 0);
    // chunk 1: n=4..7. imcol reads t4[n4..7] (untouched); t15mm writes u[n4..7] over consumed t4[n2..3]
    imcol_k <<<dim3(HH,4,4), 256, 0, stream>>>(t3, buf, 4);
    t15mm_k <<<dim3(98,4,4), 256, 0, stream>>>(buf, Wfb, u, 4);
    final_k <<<dim3(HWS/64, CC/64, NB), 256, 0, stream>>>(x, t5, w9, u, d_out, flag);
}

// Round 6
// 573.281 us; speedup vs baseline: 1.6582x; 1.1303x over previous
//
#include <hip/hip_runtime.h>
#include <hip/hip_bf16.h>

#define NB 8
#define CC 128
#define HH 112
#define WW 112
#define HWS (HH*WW)            // 12544
#define PLANE (CC*HWS)         // 1605632
#define TOT (NB*PLANE)         // 12845056

typedef __attribute__((ext_vector_type(8))) short short8v;
typedef __attribute__((ext_vector_type(4))) float float4v;

__device__ __forceinline__ float bflo(unsigned u){ return __uint_as_float(u<<16); }
__device__ __forceinline__ float bfhi(unsigned u){ return __uint_as_float(u & 0xffff0000u); }
__device__ __forceinline__ float ldv(const float* p, size_t i){ return p[i]; }
__device__ __forceinline__ float ldv(const ushort* p, size_t i){ return __uint_as_float(((unsigned)p[i])<<16); }
__device__ __forceinline__ void ld8(const ushort* p, float* v){
    uint4 u0 = *((const uint4*)p);
    v[0]=bflo(u0.x); v[1]=bfhi(u0.x); v[2]=bflo(u0.y); v[3]=bfhi(u0.y);
    v[4]=bflo(u0.z); v[5]=bfhi(u0.z); v[6]=bflo(u0.w); v[7]=bfhi(u0.w);
}
__device__ __forceinline__ void ld8(const float* p, float* v){
    float4 a = *((const float4*)p); float4 b = *((const float4*)(p+4));
    v[0]=a.x; v[1]=a.y; v[2]=a.z; v[3]=a.w; v[4]=b.x; v[5]=b.y; v[6]=b.z; v[7]=b.w;
}
__device__ __forceinline__ ushort f2bf(float f){
    unsigned u = __float_as_uint(f);
    return (ushort)((u + 0x7fffu + ((u>>16)&1u)) >> 16);
}
__device__ __forceinline__ void stv(float* o, size_t i, float v){ o[i]=v; }
__device__ __forceinline__ void stv(ushort* o, size_t i, float v){ o[i]=f2bf(v); }

// ---------------- K0: dtype probe. flag=1 -> inputs are fp32 ----------------
__global__ __launch_bounds__(256) void detect_k(const ushort* __restrict__ x, int* __restrict__ flag){
    __shared__ int cnt;
    if (threadIdx.x==0) cnt = 0;
    __syncthreads();
    int bad = 0;
    for (int i = threadIdx.x; i < 2048; i += 256){
        float v = ldv(x, i);
        if (!(v > -1e4f && v < 1e4f)) bad++;
    }
    atomicAdd(&cnt, bad);
    __syncthreads();
    if (threadIdx.x==0) *flag = (cnt > 64) ? 1 : 0;
}

// ---------------- KW1: Wpk[o][kappa=k*128+i] = bf16(w3[o,i,0,k]) ----------------
template<typename ET>
__device__ __forceinline__ void wpack_body(const ET* __restrict__ w3, ushort* __restrict__ Wpk){
    int idx = blockIdx.x*256 + threadIdx.x;
    if (idx < CC*384){
        int o = idx/384, kap = idx - o*384;
        int k = kap>>7, i = kap&127;
        Wpk[idx] = f2bf(ldv(w3, (o*128+i)*3 + k));
    }
}
__global__ __launch_bounds__(256) void wpack_k(const void* w3, ushort* Wpk, const int* fl){
    if (*fl) wpack_body((const float*)w3, Wpk); else wpack_body((const ushort*)w3, Wpk);
}

// ---------------- KB: Bbig[s][kappa] = bf16(silu(x)[i, y, x+2k-2]), fragment-ordered im2col ----------------
// NOTE: k=1 slice (kappa=128+i) == bf16(silu(x)[i, y, x]) — reused by final2_k as the t14 B-operand.
template<typename ET>
__device__ __forceinline__ void bbig_body(const ET* __restrict__ x, ushort* __restrict__ Bbig){
    int y = blockIdx.x, n = blockIdx.y;
    __shared__ ushort row[CC*120];
    const ET* xb = x + (size_t)n*PLANE + y*WW;
    for (int idx=threadIdx.x; idx<CC*WW; idx+=256){
        int i = idx/WW, xx = idx - i*WW;
        float v = ldv(xb, (size_t)i*HWS + xx);
        float sv = v * (1.f/(1.f+expf(-v)));
        row[i*120 + xx + 2] = f2bf(sv);
    }
    for (int idx=threadIdx.x; idx<CC*4; idx+=256){
        int i = idx>>2, j = idx&3;
        row[i*120 + (j<2 ? j : j+112)] = 0;
    }
    __syncthreads();
    ushort* ob = Bbig + ((size_t)(n*HWS + y*WW))*384;
    for (int idx=threadIdx.x; idx<WW*48; idx+=256){
        int xx = idx/48, c8 = idx - xx*48;
        int k = c8>>4, i0 = (c8&15)<<3, xp = xx + 2*k;
        ushort tmp[8];
        #pragma unroll
        for (int j=0;j<8;j++) tmp[j] = row[(i0+j)*120 + xp];
        *((short8v*)(ob + (size_t)xx*384 + c8*8)) = *((const short8v*)tmp);
    }
}
__global__ __launch_bounds__(256) void bbig_k(const void* x, ushort* Bbig, const int* fl){
    if (*fl) bbig_body((const float*)x, Bbig); else bbig_body((const ushort*)x, Bbig);
}

// ---------------- K2: t3 = A(128x384) * Bbig(384 x s) per n, LDS-free MFMA GEMM -> bf16 ----------------
__global__ __launch_bounds__(256) void conv3mm_k(const ushort* __restrict__ Bbig, const ushort* __restrict__ Wpk,
                                                 ushort* __restrict__ t3){
    int sb = blockIdx.x;        // 0..97
    int n  = blockIdx.y;
    int wid = threadIdx.x >> 6, lane = threadIdx.x & 63;
    int l15 = lane & 15, quad = lane >> 4;
    int s0 = sb*128 + wid*32;
    const ushort* bbase = Bbig + ((size_t)(n*HWS) + s0 + l15)*384 + quad*8;
    const ushort* abase = Wpk + (size_t)l15*384 + quad*8;
    float4v acc[8][2] = {};
    #pragma unroll
    for (int kc=0; kc<12; kc++){
        short8v b0 = *((const short8v*)(bbase + kc*32));
        short8v b1 = *((const short8v*)(bbase + 16*384 + kc*32));
        #pragma unroll
        for (int mt=0; mt<8; mt++){
            short8v a = *((const short8v*)(abase + (size_t)mt*16*384 + kc*32));
            acc[mt][0] = __builtin_amdgcn_mfma_f32_16x16x32_bf16(a, b0, acc[mt][0], 0,0,0);
            acc[mt][1] = __builtin_amdgcn_mfma_f32_16x16x32_bf16(a, b1, acc[mt][1], 0,0,0);
        }
    }
    ushort* tb = t3 + (size_t)n*PLANE;
    #pragma unroll
    for (int mt=0; mt<8; mt++){
        #pragma unroll
        for (int nt=0; nt<2; nt++){
            #pragma unroll
            for (int r=0; r<4; r++){
                int o = mt*16 + quad*4 + r;
                int s = s0 + nt*16 + l15;
                tb[(size_t)o*HWS + s] = f2bf(acc[mt][nt][r]);
            }
        }
    }
}

// ---------------- K3: depthwise conv(7,1) dil=(3,1) pad=(9,0), bf16 in/out, in-place safe ----------------
template<typename ET>
__device__ __forceinline__ void dwconv_body(const ushort* __restrict__ t3, const ET* __restrict__ w4,
                                            ushort* __restrict__ t4){
    int c = blockIdx.x & 127, n = blockIdx.x >> 7;
    __shared__ ushort pl[HWS];
    const ushort* src = t3 + (size_t)n*PLANE + c*HWS;
    for (int i=threadIdx.x; i<HWS/8; i+=256)
        ((short8v*)pl)[i] = ((const short8v*)src)[i];
    float wk[7];
    #pragma unroll
    for (int k=0;k<7;k++) wk[k]=ldv(w4, c*7+k);
    __syncthreads();
    ushort* dst = t4 + (size_t)n*PLANE + c*HWS;
    for (int i=threadIdx.x;i<HWS;i+=256){
        int y = i/WW, x = i - y*WW;
        float acc=0.f;
        #pragma unroll
        for (int k=0;k<7;k++){
            int yy = y-9+3*k;
            if (yy>=0 && yy<HH) acc = fmaf(wk[k], ldv(pl, yy*WW+x), acc);
        }
        dst[i]=f2bf(acc);
    }
}
__global__ __launch_bounds__(256) void dwconv_k(const ushort* t3, const void* w4, ushort* t4, const int* fl){
    if (*fl) dwconv_body(t3, (const float*)w4, t4); else dwconv_body(t3, (const ushort*)w4, t4);
}

// ---------------- KW2: Wfb[o][cl*7+k] = bf16(w15[o, cl*7+k] * w10[32g+cl, k]) ----------------
template<typename ET>
__device__ __forceinline__ void fusew_body(const ET* __restrict__ w10, const ET* __restrict__ w15,
                                           ushort* __restrict__ Wfb){
    int idx = blockIdx.x*256+threadIdx.x;
    if (idx < CC*224){
        int o = idx / 224, r = idx - o*224;
        int g = o >> 5;
        int cl = r/7, k = r - cl*7;
        int c = g*32 + cl;
        Wfb[idx] = f2bf(ldv(w15, o*224 + r) * ldv(w10, c*7+k));
    }
}
__global__ __launch_bounds__(256) void fusew_k(const void* w10, const void* w15, ushort* Wfb, const int* fl){
    if (*fl) fusew_body((const float*)w10, (const float*)w15, Wfb);
    else     fusew_body((const ushort*)w10, (const ushort*)w15, Wfb);
}

// ---------------- K6 (fused): u[n, g*32+o, y, :] = Wfb(32x224) * gather(t4) — LDS transpose + MFMA ----------------
// LDS sm[x][kappa], row stride 232 ushorts (464 B): b128 fragment reads are 16B-aligned and
// spread 8 dwords/bank (conflict-free); scalar gather writes pay ~8-way (acceptable, paid once).
__global__ __launch_bounds__(256) void t15f_k(const ushort* __restrict__ t4, const ushort* __restrict__ Wfb,
                                              ushort* __restrict__ u){
    int y = blockIdx.x, g = blockIdx.y, n = blockIdx.z;
    __shared__ ushort sm[WW*232];
    const ushort* tb = t4 + (size_t)n*PLANE;
    for (int idx=threadIdx.x; idx<224*WW; idx+=256){
        int kap = idx/WW, x = idx - kap*WW;
        int cl = kap/7, k = kap - cl*7;
        int row = y + 2*k - 6;
        int ch = (g*32 + cl - 2) & 127;
        sm[x*232 + kap] = (row>=0 && row<HH) ? tb[(size_t)ch*HWS + row*WW + x] : (ushort)0;
    }
    __syncthreads();
    int wid = threadIdx.x>>6, lane = threadIdx.x&63;
    int l15 = lane&15, quad = lane>>4;
    const ushort* abase = Wfb + (size_t)(g*32 + l15)*224 + quad*8;
    ushort* ub = u + ((size_t)n*CC + g*32)*HWS + y*WW;
    for (int stile = wid; stile < 7; stile += 4){
        float4v acc0 = {0.f,0.f,0.f,0.f}, acc1 = {0.f,0.f,0.f,0.f};
        const ushort* bbase = sm + (stile*16 + l15)*232 + quad*8;
        #pragma unroll
        for (int kc=0; kc<7; kc++){
            short8v b  = *((const short8v*)(bbase + kc*32));
            short8v a0 = *((const short8v*)(abase + kc*32));
            short8v a1 = *((const short8v*)(abase + 16*224 + kc*32));
            acc0 = __builtin_amdgcn_mfma_f32_16x16x32_bf16(a0, b, acc0, 0,0,0);
            acc1 = __builtin_amdgcn_mfma_f32_16x16x32_bf16(a1, b, acc1, 0,0,0);
        }
        int s = stile*16 + l15;
        #pragma unroll
        for (int r=0;r<4;r++){
            ub[(size_t)(quad*4+r)*HWS + s]      = f2bf(acc0[r]);
            ub[(size_t)(16+quad*4+r)*HWS + s]   = f2bf(acc1[r]);
        }
    }
}

// ---------------- K4: t5[n,ci,cj] += sum_s sigmoid(x[ci,s]) * x[cj,s] — LDS-free MFMA, K-split x49 ----------------
template<typename ET>
__device__ __forceinline__ void t5mm_body(const ET* __restrict__ x, float* __restrict__ t5){
    int ks = blockIdx.x, n = blockIdx.y;    // ks 0..48, 12544 = 49*256
    int wid = threadIdx.x>>6, lane = threadIdx.x&63;
    int l15 = lane&15, quad = lane>>4;
    const ET* xn = x + (size_t)n*PLANE;
    float4v acc[2][8] = {};
    for (int t=0; t<8; t++){
        int sb = ks*256 + t*32 + quad*8;
        short8v afr[2];
        #pragma unroll
        for (int mt=0; mt<2; mt++){
            int row = wid*32 + mt*16 + l15;
            float v[8]; ld8(xn + (size_t)row*HWS + sb, v);
            ushort tmp[8];
            #pragma unroll
            for (int j=0;j<8;j++) tmp[j] = f2bf(1.f/(1.f+expf(-v[j])));
            afr[mt] = *((const short8v*)tmp);
        }
        #pragma unroll
        for (int nt=0; nt<8; nt++){
            int row = nt*16 + l15;
            float v[8]; ld8(xn + (size_t)row*HWS + sb, v);
            ushort tmp[8];
            #pragma unroll
            for (int j=0;j<8;j++) tmp[j] = f2bf(v[j]);
            short8v bfr = *((const short8v*)tmp);
            acc[0][nt] = __builtin_amdgcn_mfma_f32_16x16x32_bf16(afr[0], bfr, acc[0][nt], 0,0,0);
            acc[1][nt] = __builtin_amdgcn_mfma_f32_16x16x32_bf16(afr[1], bfr, acc[1][nt], 0,0,0);
        }
    }
    float* t5n = t5 + n*16384;
    #pragma unroll
    for (int mt=0; mt<2; mt++){
        #pragma unroll
        for (int nt=0; nt<8; nt++){
            #pragma unroll
            for (int r=0; r<4; r++){
                int ci = wid*32 + mt*16 + quad*4 + r;
                int cj = nt*16 + l15;
                atomicAdd(&t5n[ci*128 + cj], acc[mt][nt][r]);
            }
        }
    }
}
__global__ __launch_bounds__(256) void t5mm_k(const void* x, float* t5, const int* fl){
    if (*fl) t5mm_body((const float*)x, t5); else t5mm_body((const ushort*)x, t5);
}

// ---------------- KC: coefb[n][d][c] = bf16(w9[c,d] * t5[n,c,d] * sc) ----------------
template<typename ET>
__device__ __forceinline__ void coefb_body(const ET* __restrict__ w9, const float* __restrict__ t5,
                                           ushort* __restrict__ coefb){
    const float sc = 7.89181775e-4f;   // 1/(sqrt(12544)*sqrt(128))
    int idx = blockIdx.x*256 + threadIdx.x;   // over 8*16384
    int n = idx >> 14, rem = idx & 16383;
    int d = rem >> 7, c = rem & 127;
    coefb[idx] = f2bf(ldv(w9, c*128 + d) * t5[n*16384 + c*128 + d] * sc);
}
__global__ __launch_bounds__(256) void coefb_k(const void* w9, const float* t5, ushort* coefb, const int* fl){
    if (*fl) coefb_body((const float*)w9, t5, coefb); else coefb_body((const ushort*)w9, t5, coefb);
}

// ---------------- K5 (MFMA): out = u[shifted] + coefb(128d x 128c) * BbigK1(128c x s) ----------------
template<typename OT>
__device__ __forceinline__ void final2_body(const ushort* __restrict__ Bbig, const ushort* __restrict__ coefb,
                                            const ushort* __restrict__ u, OT* __restrict__ out){
    int sb = blockIdx.x, n = blockIdx.y;
    int wid = threadIdx.x>>6, lane = threadIdx.x&63;
    int l15 = lane&15, quad = lane>>4;
    int s0 = sb*128 + wid*32;
    const ushort* bbase = Bbig + ((size_t)(n*HWS) + s0 + l15)*384 + 128 + quad*8;   // k=1 slice = silu(x)
    const ushort* abase = coefb + (size_t)n*16384 + (size_t)l15*128 + quad*8;
    float4v acc[8][2] = {};
    #pragma unroll
    for (int kc=0; kc<4; kc++){
        short8v b0 = *((const short8v*)(bbase + kc*32));
        short8v b1 = *((const short8v*)(bbase + 16*384 + kc*32));
        #pragma unroll
        for (int mt=0; mt<8; mt++){
            short8v a = *((const short8v*)(abase + mt*16*128 + kc*32));
            acc[mt][0] = __builtin_amdgcn_mfma_f32_16x16x32_bf16(a, b0, acc[mt][0], 0,0,0);
            acc[mt][1] = __builtin_amdgcn_mfma_f32_16x16x32_bf16(a, b1, acc[mt][1], 0,0,0);
        }
    }
    #pragma unroll
    for (int mt=0; mt<8; mt++){
        #pragma unroll
        for (int nt=0; nt<2; nt++){
            int s = s0 + nt*16 + l15;
            int y = s/WW, xx = s - y*WW;
            int ys = y+2; if (ys>=HH) ys-=HH;
            int xs = xx-2; if (xs<0) xs+=WW;
            #pragma unroll
            for (int r=0; r<4; r++){
                int d = mt*16 + quad*4 + r;
                float val = ldv(u, ((size_t)n*CC+d)*HWS + ys*WW + xs) + acc[mt][nt][r];
                stv(out, ((size_t)n*CC+d)*HWS + s, val);
            }
        }
    }
}
__global__ __launch_bounds__(256) void final2_k(const ushort* Bbig, const ushort* coefb,
                                                const ushort* u, void* out, const int* fl){
    if (*fl) final2_body(Bbig, coefb, u, (float*)out);
    else     final2_body(Bbig, coefb, u, (ushort*)out);
}

extern "C" void kernel_launch(void* const* d_in, const int* in_sizes, int n_in,
                              void* d_out, int out_size, void* d_ws, size_t ws_size,
                              hipStream_t stream) {
    const void* x   = d_in[0];
    const void* w3  = d_in[1];
    const void* w4  = d_in[2];
    const void* w9  = d_in[3];
    const void* w10 = d_in[4];
    const void* w15 = d_in[5];

    ushort* t3   = (ushort*)d_ws;                  // TOT ushorts (t3, then t4 in-place)
    ushort* Bbig = t3 + TOT;                       // 3*TOT ushorts (77MB; alive to the end)
    ushort* u    = Bbig + (size_t)3*TOT;           // TOT ushorts
    float*  t5   = (float*)(u + TOT);              // 8*16384 floats
    ushort* coefb= (ushort*)(t5 + NB*CC*CC);       // 8*16384 ushorts
    ushort* Wfb  = coefb + NB*CC*CC;               // 128*224
    ushort* Wpk  = Wfb + CC*224;                   // 128*384
    int* flag    = (int*)(Wpk + CC*384);

    detect_k<<<1, 256, 0, stream>>>((const ushort*)x, flag);
    hipMemsetAsync(t5, 0, NB*CC*CC*sizeof(float), stream);

    wpack_k <<<192, 256, 0, stream>>>(w3, Wpk, flag);
    fusew_k <<<112, 256, 0, stream>>>(w10, w15, Wfb, flag);
    bbig_k  <<<dim3(HH,NB), 256, 0, stream>>>(x, Bbig, flag);
    conv3mm_k<<<dim3(98,NB), 256, 0, stream>>>(Bbig, Wpk, t3);
    dwconv_k<<<NB*CC, 256, 0, stream>>>(t3, w4, t3, flag);   // in-place: t3 now holds t4
    t5mm_k  <<<dim3(49,NB), 256, 0, stream>>>(x, t5, flag);
    coefb_k <<<NB*CC*CC/256, 256, 0, stream>>>(w9, t5, coefb, flag);
    t15f_k  <<<dim3(HH,4,NB), 256, 0, stream>>>(t3, Wfb, u);
    final2_k<<<dim3(98,NB), 256, 0, stream>>>(Bbig, coefb, u, d_out, flag);
}

// Round 7
// 428.489 us; speedup vs baseline: 2.2185x; 1.3379x over previous
//
#include <hip/hip_runtime.h>
#include <hip/hip_bf16.h>

#define NB 8
#define CC 128
#define HH 112
#define WW 112
#define HWS (HH*WW)            // 12544
#define PLANE (CC*HWS)         // 1605632
#define TOT (NB*PLANE)         // 12845056

typedef __attribute__((ext_vector_type(8))) short short8v;
typedef __attribute__((ext_vector_type(4))) float float4v;

__device__ __forceinline__ float bflo(unsigned u){ return __uint_as_float(u<<16); }
__device__ __forceinline__ float bfhi(unsigned u){ return __uint_as_float(u & 0xffff0000u); }
__device__ __forceinline__ float ldv(const float* p, size_t i){ return p[i]; }
__device__ __forceinline__ float ldv(const ushort* p, size_t i){ return __uint_as_float(((unsigned)p[i])<<16); }
__device__ __forceinline__ void ld8(const ushort* p, float* v){
    uint4 u0 = *((const uint4*)p);
    v[0]=bflo(u0.x); v[1]=bfhi(u0.x); v[2]=bflo(u0.y); v[3]=bfhi(u0.y);
    v[4]=bflo(u0.z); v[5]=bfhi(u0.z); v[6]=bflo(u0.w); v[7]=bfhi(u0.w);
}
__device__ __forceinline__ void ld8(const float* p, float* v){
    float4 a = *((const float4*)p); float4 b = *((const float4*)(p+4));
    v[0]=a.x; v[1]=a.y; v[2]=a.z; v[3]=a.w; v[4]=b.x; v[5]=b.y; v[6]=b.z; v[7]=b.w;
}
__device__ __forceinline__ ushort f2bf(float f){
    unsigned u = __float_as_uint(f);
    return (ushort)((u + 0x7fffu + ((u>>16)&1u)) >> 16);
}
__device__ __forceinline__ void stv(float* o, size_t i, float v){ o[i]=v; }
__device__ __forceinline__ void stv(ushort* o, size_t i, float v){ o[i]=f2bf(v); }

// ---------------- K0: dtype probe. flag=1 -> inputs are fp32 ----------------
__global__ __launch_bounds__(256) void detect_k(const ushort* __restrict__ x, int* __restrict__ flag){
    __shared__ int cnt;
    if (threadIdx.x==0) cnt = 0;
    __syncthreads();
    int bad = 0;
    for (int i = threadIdx.x; i < 2048; i += 256){
        float v = ldv(x, i);
        if (!(v > -1e4f && v < 1e4f)) bad++;
    }
    atomicAdd(&cnt, bad);
    __syncthreads();
    if (threadIdx.x==0) *flag = (cnt > 64) ? 1 : 0;
}

// ---------------- KW1: Wpk[o][kappa=k*128+i] = bf16(w3[o,i,0,k]) ----------------
template<typename ET>
__device__ __forceinline__ void wpack_body(const ET* __restrict__ w3, ushort* __restrict__ Wpk){
    int idx = blockIdx.x*256 + threadIdx.x;
    if (idx < CC*384){
        int o = idx/384, kap = idx - o*384;
        int k = kap>>7, i = kap&127;
        Wpk[idx] = f2bf(ldv(w3, (o*128+i)*3 + k));
    }
}
__global__ __launch_bounds__(256) void wpack_k(const void* w3, ushort* Wpk, const int* fl){
    if (*fl) wpack_body((const float*)w3, Wpk); else wpack_body((const ushort*)w3, Wpk);
}

// ---------------- KB: Bbig[s][kappa] = bf16(silu(x)[i, y, x+2k-2]) ----------------
// k=1 slice (kappa=128+i) == bf16(silu(x)[i, s]) — reused by final2_k as the t14 B-operand.
template<typename ET>
__device__ __forceinline__ void bbig_body(const ET* __restrict__ x, ushort* __restrict__ Bbig){
    int y = blockIdx.x, n = blockIdx.y;
    __shared__ ushort row[CC*120];
    const ET* xb = x + (size_t)n*PLANE + y*WW;
    for (int idx=threadIdx.x; idx<CC*WW; idx+=256){
        int i = idx/WW, xx = idx - i*WW;
        float v = ldv(xb, (size_t)i*HWS + xx);
        float sv = v * (1.f/(1.f+expf(-v)));
        row[i*120 + xx + 2] = f2bf(sv);
    }
    for (int idx=threadIdx.x; idx<CC*4; idx+=256){
        int i = idx>>2, j = idx&3;
        row[i*120 + (j<2 ? j : j+112)] = 0;
    }
    __syncthreads();
    ushort* ob = Bbig + ((size_t)(n*HWS + y*WW))*384;
    for (int idx=threadIdx.x; idx<WW*48; idx+=256){
        int xx = idx/48, c8 = idx - xx*48;
        int k = c8>>4, i0 = (c8&15)<<3, xp = xx + 2*k;
        ushort tmp[8];
        #pragma unroll
        for (int j=0;j<8;j++) tmp[j] = row[(i0+j)*120 + xp];
        *((short8v*)(ob + (size_t)xx*384 + c8*8)) = *((const short8v*)tmp);
    }
}
__global__ __launch_bounds__(256) void bbig_k(const void* x, ushort* Bbig, const int* fl){
    if (*fl) bbig_body((const float*)x, Bbig); else bbig_body((const ushort*)x, Bbig);
}

// ---------------- K2: t3T[n][s][o] = A(128x384) * Bbig(384 x s) — MFMA, channel-contiguous store ----------------
__global__ __launch_bounds__(256) void conv3mm_k(const ushort* __restrict__ Bbig, const ushort* __restrict__ Wpk,
                                                 ushort* __restrict__ t3T){
    int sb = blockIdx.x;        // 0..97
    int n  = blockIdx.y;
    int wid = threadIdx.x >> 6, lane = threadIdx.x & 63;
    int l15 = lane & 15, quad = lane >> 4;
    int s0 = sb*128 + wid*32;
    const ushort* bbase = Bbig + ((size_t)(n*HWS) + s0 + l15)*384 + quad*8;
    const ushort* abase = Wpk + (size_t)l15*384 + quad*8;
    float4v acc[8][2] = {};
    #pragma unroll
    for (int kc=0; kc<12; kc++){
        short8v b0 = *((const short8v*)(bbase + kc*32));
        short8v b1 = *((const short8v*)(bbase + 16*384 + kc*32));
        #pragma unroll
        for (int mt=0; mt<8; mt++){
            short8v a = *((const short8v*)(abase + (size_t)mt*16*384 + kc*32));
            acc[mt][0] = __builtin_amdgcn_mfma_f32_16x16x32_bf16(a, b0, acc[mt][0], 0,0,0);
            acc[mt][1] = __builtin_amdgcn_mfma_f32_16x16x32_bf16(a, b1, acc[mt][1], 0,0,0);
        }
    }
    ushort* tb = t3T + (size_t)n*PLANE;
    #pragma unroll
    for (int nt=0; nt<2; nt++){
        int s = s0 + nt*16 + l15;
        ushort* rowp = tb + (size_t)s*128 + quad*4;
        #pragma unroll
        for (int mt=0; mt<8; mt++){
            ushort4 v;
            v.x = f2bf(acc[mt][nt][0]); v.y = f2bf(acc[mt][nt][1]);
            v.z = f2bf(acc[mt][nt][2]); v.w = f2bf(acc[mt][nt][3]);
            *((ushort4*)(rowp + mt*16)) = v;
        }
    }
}

// ---------------- KWD: wdp[k*128+c] = w4[c,k] (fp32) ----------------
template<typename ET>
__device__ __forceinline__ void wdpack_body(const ET* __restrict__ w4, float* __restrict__ wdp){
    int idx = blockIdx.x*256 + threadIdx.x;
    if (idx < 896){ int k = idx >> 7, c = idx & 127; wdp[idx] = ldv(w4, c*7 + k); }
}
__global__ __launch_bounds__(256) void wdpack_k(const void* w4, float* wdp, const int* fl){
    if (*fl) wdpack_body((const float*)w4, wdp); else wdpack_body((const ushort*)w4, wdp);
}

// ---------------- K3: depthwise conv(7,1) dil=(3,1) pad=(9,0) on transposed layout, LDS-free ----------------
__global__ __launch_bounds__(256) void dwconvT_k(const ushort* __restrict__ t3T, const float* __restrict__ wdp,
                                                 ushort* __restrict__ t4T){
    int by = blockIdx.x, n = blockIdx.y;
    int y = (by>>3) + (by&7)*14;   // XCD-contiguous y chunks
    const ushort* tb = t3T + (size_t)n*PLANE;
    ushort* ob = t4T + (size_t)n*PLANE + (size_t)y*WW*128;
    for (int it = threadIdx.x; it < WW*16; it += 256){
        int c8 = it & 15, x = it >> 4;
        int coff = c8*8;
        float acc8[8] = {0.f,0.f,0.f,0.f,0.f,0.f,0.f,0.f};
        #pragma unroll
        for (int k=0;k<7;k++){
            int row = y - 9 + 3*k;
            if (row < 0 || row >= HH) continue;
            float v[8]; ld8(tb + ((size_t)row*WW + x)*128 + coff, v);
            const float* wp = wdp + k*128 + coff;
            #pragma unroll
            for (int j=0;j<8;j++) acc8[j] = fmaf(wp[j], v[j], acc8[j]);
        }
        ushort tmp[8];
        #pragma unroll
        for (int j=0;j<8;j++) tmp[j] = f2bf(acc8[j]);
        *((short8v*)(ob + (size_t)x*128 + coff)) = *((const short8v*)tmp);
    }
}

// ---------------- KW2: Wfb[o][cl*7+k] = bf16(w15[o, cl*7+k] * w10[32g+cl, k]) ----------------
template<typename ET>
__device__ __forceinline__ void fusew_body(const ET* __restrict__ w10, const ET* __restrict__ w15,
                                           ushort* __restrict__ Wfb){
    int idx = blockIdx.x*256+threadIdx.x;
    if (idx < CC*224){
        int o = idx / 224, r = idx - o*224;
        int g = o >> 5;
        int cl = r/7, k = r - cl*7;
        int c = g*32 + cl;
        Wfb[idx] = f2bf(ldv(w15, o*224 + r) * ldv(w10, c*7+k));
    }
}
__global__ __launch_bounds__(256) void fusew_k(const void* w10, const void* w15, ushort* Wfb, const int* fl){
    if (*fl) fusew_body((const float*)w10, (const float*)w15, Wfb);
    else     fusew_body((const ushort*)w10, (const ushort*)w15, Wfb);
}

// ---------------- KWA: Wfa fragment pack. A[w][k][q][mt][l15][j] over c'-aligned 32-blocks ----------------
// wave w's inputs c' = (32w + cl - 2) mod 128, cl in [0,32): block q=1 (c'-block w): j in [0,30) -> cl=j+2;
// block q=0 (c'-block (w+3)&3): j in {30,31} -> cl=j-30; zero elsewhere.
__global__ __launch_bounds__(256) void wfapack_k(const ushort* __restrict__ Wfb, ushort* __restrict__ Wfa){
    int idx = blockIdx.x*256 + threadIdx.x;   // 4*7*2*2*16*32 = 57344
    if (idx >= 57344) return;
    int j   = idx & 31;
    int l15 = (idx >> 5) & 15;
    int mt  = (idx >> 9) & 1;
    int q   = (idx >> 10) & 1;
    int k   = (idx >> 11) % 7;
    int w   = idx / 14336;
    int o = w*32 + mt*16 + l15;
    int cl = -1;
    if (q==1){ if (j < 30) cl = j + 2; }
    else     { if (j >= 30) cl = j - 30; }
    Wfa[idx] = (cl >= 0) ? Wfb[o*224 + cl*7 + k] : (ushort)0;
}

// ---------------- K6: u[n, 32w+o, y, x] = sum_k Wfa_k * t4T[n, y+2k-6, x, :] — gather-free MFMA ----------------
__global__ __launch_bounds__(256) void t15v2_k(const ushort* __restrict__ t4T, const ushort* __restrict__ Wfa,
                                               ushort* __restrict__ u){
    int by = blockIdx.x, n = blockIdx.y;
    int y = (by>>3) + (by&7)*14;   // XCD-contiguous y chunks
    int w = threadIdx.x >> 6, lane = threadIdx.x & 63;
    int l15 = lane & 15, quad = lane >> 4;
    int qlo = (w+3)&3;
    float4v acc[7][2] = {};
    const ushort* tbase = t4T + (size_t)n*PLANE;
    for (int k=0;k<7;k++){
        int row = y + 2*k - 6;
        if (row < 0 || row >= HH) continue;
        const ushort* af = Wfa + (w*7 + k)*2048 + l15*32 + quad*8;
        short8v A00 = *((const short8v*)(af));          // q=0, mt=0
        short8v A01 = *((const short8v*)(af + 512));    // q=0, mt=1
        short8v A10 = *((const short8v*)(af + 1024));   // q=1, mt=0
        short8v A11 = *((const short8v*)(af + 1536));   // q=1, mt=1
        const ushort* rbase = tbase + ((size_t)row*WW + l15)*128 + quad*8;
        #pragma unroll
        for (int st=0; st<7; st++){
            const ushort* bp = rbase + st*16*128;
            short8v B0 = *((const short8v*)(bp + qlo*32));
            short8v B1 = *((const short8v*)(bp + w*32));
            acc[st][0] = __builtin_amdgcn_mfma_f32_16x16x32_bf16(A00, B0, acc[st][0], 0,0,0);
            acc[st][1] = __builtin_amdgcn_mfma_f32_16x16x32_bf16(A01, B0, acc[st][1], 0,0,0);
            acc[st][0] = __builtin_amdgcn_mfma_f32_16x16x32_bf16(A10, B1, acc[st][0], 0,0,0);
            acc[st][1] = __builtin_amdgcn_mfma_f32_16x16x32_bf16(A11, B1, acc[st][1], 0,0,0);
        }
    }
    ushort* ub = u + ((size_t)n*CC + w*32)*HWS + (size_t)y*WW;
    #pragma unroll
    for (int st=0; st<7; st++){
        int s = st*16 + l15;
        #pragma unroll
        for (int mt=0; mt<2; mt++)
            #pragma unroll
            for (int r=0;r<4;r++)
                ub[(size_t)(mt*16+quad*4+r)*HWS + s] = f2bf(acc[st][mt][r]);
    }
}

// ---------------- K4: t5[n,ci,cj] += sum_s sigmoid(x[ci,s]) * x[cj,s] — LDS-free MFMA, K-split x49 ----------------
template<typename ET>
__device__ __forceinline__ void t5mm_body(const ET* __restrict__ x, float* __restrict__ t5){
    int ks = blockIdx.x, n = blockIdx.y;    // ks 0..48, 12544 = 49*256
    int wid = threadIdx.x>>6, lane = threadIdx.x&63;
    int l15 = lane&15, quad = lane>>4;
    const ET* xn = x + (size_t)n*PLANE;
    float4v acc[2][8] = {};
    for (int t=0; t<8; t++){
        int sb = ks*256 + t*32 + quad*8;
        short8v afr[2];
        #pragma unroll
        for (int mt=0; mt<2; mt++){
            int row = wid*32 + mt*16 + l15;
            float v[8]; ld8(xn + (size_t)row*HWS + sb, v);
            ushort tmp[8];
            #pragma unroll
            for (int j=0;j<8;j++) tmp[j] = f2bf(1.f/(1.f+expf(-v[j])));
            afr[mt] = *((const short8v*)tmp);
        }
        #pragma unroll
        for (int nt=0; nt<8; nt++){
            int row = nt*16 + l15;
            float v[8]; ld8(xn + (size_t)row*HWS + sb, v);
            ushort tmp[8];
            #pragma unroll
            for (int j=0;j<8;j++) tmp[j] = f2bf(v[j]);
            short8v bfr = *((const short8v*)tmp);
            acc[0][nt] = __builtin_amdgcn_mfma_f32_16x16x32_bf16(afr[0], bfr, acc[0][nt], 0,0,0);
            acc[1][nt] = __builtin_amdgcn_mfma_f32_16x16x32_bf16(afr[1], bfr, acc[1][nt], 0,0,0);
        }
    }
    float* t5n = t5 + n*16384;
    #pragma unroll
    for (int mt=0; mt<2; mt++){
        #pragma unroll
        for (int nt=0; nt<8; nt++){
            #pragma unroll
            for (int r=0; r<4; r++){
                int ci = wid*32 + mt*16 + quad*4 + r;
                int cj = nt*16 + l15;
                atomicAdd(&t5n[ci*128 + cj], acc[mt][nt][r]);
            }
        }
    }
}
__global__ __launch_bounds__(256) void t5mm_k(const void* x, float* t5, const int* fl){
    if (*fl) t5mm_body((const float*)x, t5); else t5mm_body((const ushort*)x, t5);
}

// ---------------- KC: coefb[n][d][c] = bf16(w9[c,d] * t5[n,c,d] * sc) ----------------
template<typename ET>
__device__ __forceinline__ void coefb_body(const ET* __restrict__ w9, const float* __restrict__ t5,
                                           ushort* __restrict__ coefb){
    const float sc = 7.89181775e-4f;   // 1/(sqrt(12544)*sqrt(128))
    int idx = blockIdx.x*256 + threadIdx.x;   // over 8*16384
    int n = idx >> 14, rem = idx & 16383;
    int d = rem >> 7, c = rem & 127;
    coefb[idx] = f2bf(ldv(w9, c*128 + d) * t5[n*16384 + c*128 + d] * sc);
}
__global__ __launch_bounds__(256) void coefb_k(const void* w9, const float* t5, ushort* coefb, const int* fl){
    if (*fl) coefb_body((const float*)w9, t5, coefb); else coefb_body((const ushort*)w9, t5, coefb);
}

// ---------------- K5 (MFMA): out = u[shifted] + coefb(128d x 128c) * BbigK1(128c x s) ----------------
template<typename OT>
__device__ __forceinline__ void final2_body(const ushort* __restrict__ Bbig, const ushort* __restrict__ coefb,
                                            const ushort* __restrict__ u, OT* __restrict__ out){
    int sb = blockIdx.x, n = blockIdx.y;
    int wid = threadIdx.x>>6, lane = threadIdx.x&63;
    int l15 = lane&15, quad = lane>>4;
    int s0 = sb*128 + wid*32;
    const ushort* bbase = Bbig + ((size_t)(n*HWS) + s0 + l15)*384 + 128 + quad*8;   // k=1 slice = silu(x)
    const ushort* abase = coefb + (size_t)n*16384 + (size_t)l15*128 + quad*8;
    float4v acc[8][2] = {};
    #pragma unroll
    for (int kc=0; kc<4; kc++){
        short8v b0 = *((const short8v*)(bbase + kc*32));
        short8v b1 = *((const short8v*)(bbase + 16*384 + kc*32));
        #pragma unroll
        for (int mt=0; mt<8; mt++){
            short8v a = *((const short8v*)(abase + mt*16*128 + kc*32));
            acc[mt][0] = __builtin_amdgcn_mfma_f32_16x16x32_bf16(a, b0, acc[mt][0], 0,0,0);
            acc[mt][1] = __builtin_amdgcn_mfma_f32_16x16x32_bf16(a, b1, acc[mt][1], 0,0,0);
        }
    }
    #pragma unroll
    for (int mt=0; mt<8; mt++){
        #pragma unroll
        for (int nt=0; nt<2; nt++){
            int s = s0 + nt*16 + l15;
            int y = s/WW, xx = s - y*WW;
            int ys = y+2; if (ys>=HH) ys-=HH;
            int xs = xx-2; if (xs<0) xs+=WW;
            #pragma unroll
            for (int r=0; r<4; r++){
                int d = mt*16 + quad*4 + r;
                float val = ldv(u, ((size_t)n*CC+d)*HWS + ys*WW + xs) + acc[mt][nt][r];
                stv(out, ((size_t)n*CC+d)*HWS + s, val);
            }
        }
    }
}
__global__ __launch_bounds__(256) void final2_k(const ushort* Bbig, const ushort* coefb,
                                                const ushort* u, void* out, const int* fl){
    if (*fl) final2_body(Bbig, coefb, u, (float*)out);
    else     final2_body(Bbig, coefb, u, (ushort*)out);
}

extern "C" void kernel_launch(void* const* d_in, const int* in_sizes, int n_in,
                              void* d_out, int out_size, void* d_ws, size_t ws_size,
                              hipStream_t stream) {
    const void* x   = d_in[0];
    const void* w3  = d_in[1];
    const void* w4  = d_in[2];
    const void* w9  = d_in[3];
    const void* w10 = d_in[4];
    const void* w15 = d_in[5];

    ushort* t3T  = (ushort*)d_ws;                  // TOT ushorts; reused as u after dwconvT consumes it
    ushort* u    = t3T;
    ushort* t4T  = t3T + TOT;                      // TOT ushorts
    ushort* Bbig = t4T + TOT;                      // 3*TOT ushorts (77MB; alive to the end)
    float*  t5   = (float*)(Bbig + (size_t)3*TOT); // 8*16384 floats
    ushort* coefb= (ushort*)(t5 + NB*CC*CC);       // 8*16384
    ushort* Wfb  = coefb + NB*CC*CC;               // 128*224
    ushort* Wpk  = Wfb + CC*224;                   // 128*384
    ushort* Wfa  = Wpk + CC*384;                   // 57344
    float*  wdp  = (float*)(Wfa + 57344);          // 896
    int* flag    = (int*)(wdp + 896);

    detect_k<<<1, 256, 0, stream>>>((const ushort*)x, flag);
    hipMemsetAsync(t5, 0, NB*CC*CC*sizeof(float), stream);

    wpack_k  <<<192, 256, 0, stream>>>(w3, Wpk, flag);
    fusew_k  <<<112, 256, 0, stream>>>(w10, w15, Wfb, flag);
    wfapack_k<<<224, 256, 0, stream>>>(Wfb, Wfa);
    wdpack_k <<<4,   256, 0, stream>>>(w4, wdp, flag);
    bbig_k   <<<dim3(HH,NB), 256, 0, stream>>>(x, Bbig, flag);
    conv3mm_k<<<dim3(98,NB), 256, 0, stream>>>(Bbig, Wpk, t3T);
    dwconvT_k<<<dim3(HH,NB), 256, 0, stream>>>(t3T, wdp, t4T);
    t5mm_k   <<<dim3(49,NB), 256, 0, stream>>>(x, t5, flag);
    coefb_k  <<<NB*CC*CC/256, 256, 0, stream>>>(w9, t5, coefb, flag);
    t15v2_k  <<<dim3(HH,NB), 256, 0, stream>>>(t4T, Wfa, u);   // u aliases dead t3T
    final2_k <<<dim3(98,NB), 256, 0, stream>>>(Bbig, coefb, u, d_out, flag);
}